// Round 15
// baseline (1499.233 us; speedup 1.0000x reference)
//
#include <hip/hip_runtime.h>
#include <hip/hip_bf16.h>

#define DI __device__ __forceinline__

typedef unsigned short u16;
typedef unsigned int u32;
typedef __attribute__((ext_vector_type(8))) short bf16x8;   // 8 bf16 in 4 VGPRs
typedef __attribute__((ext_vector_type(4))) short bf16x4;   // 4 bf16 in 2 VGPRs
typedef __attribute__((ext_vector_type(4))) float f32x4;

// ---- model constants ----
#define B_   2
#define T_   2048
#define D_   1024
#define H_   16
#define KH_  4
#define HD_  64
#define F_   4096
#define L_   4
#define V_   32000
#define M_   (B_ * T_)          // 4096 tokens
#define QKVN (H_*HD_ + 2*KH_*HD_)  // 1536

DI u16 f2bf(float f) {
  __hip_bfloat16 h = __float2bfloat16(f);
  return *reinterpret_cast<u16*>(&h);
}

DI float bf2f(u16 b) {
  __hip_bfloat16 h = *reinterpret_cast<__hip_bfloat16*>(&b);
  return __bfloat162float(h);
}

DI void gl_lds16(const void* g, void* l) {
  __builtin_amdgcn_global_load_lds(
      (const __attribute__((address_space(1))) u32*)g,
      (__attribute__((address_space(3))) u32*)l, 16, 0, 0);
}

#define BARRIER() do { asm volatile("" ::: "memory"); __builtin_amdgcn_s_barrier(); asm volatile("" ::: "memory"); } while (0)
#define LGK0()    asm volatile("s_waitcnt lgkmcnt(0)" ::: "memory")
#define VMC(n)    asm volatile("s_waitcnt vmcnt(" #n ")" ::: "memory")
#define PRIO(p)   __builtin_amdgcn_s_setprio(p)

// ---------------- embedding: x = embed[ids] + pos ----------------
__global__ __launch_bounds__(256) void embed_kernel(const int* __restrict__ ids,
                                                    const float* __restrict__ ew,
                                                    const float* __restrict__ pw,
                                                    float* __restrict__ x) {
  const int row = blockIdx.x;          // 0..4095
  const int t = row & (T_ - 1);
  const int id = ids[row];
  float4 e = reinterpret_cast<const float4*>(ew + (size_t)id * D_)[threadIdx.x];
  float4 p = reinterpret_cast<const float4*>(pw + (size_t)t * D_)[threadIdx.x];
  e.x += p.x; e.y += p.y; e.z += p.z; e.w += p.w;
  reinterpret_cast<float4*>(x + (size_t)row * D_)[threadIdx.x] = e;
}

// ---------------- f32 -> bf16 elementwise (embed table) ----------------
__global__ __launch_bounds__(256) void conv_kernel(const float* __restrict__ W,
                                                   u16* __restrict__ Wb) {
  const size_t i = (size_t)blockIdx.x * 256 + threadIdx.x;   // float4 index
  float4 v = reinterpret_cast<const float4*>(W)[i];
  ushort4 ov;
  ov.x = f2bf(v.x); ov.y = f2bf(v.y); ov.z = f2bf(v.z); ov.w = f2bf(v.w);
  reinterpret_cast<ushort4*>(Wb)[i] = ov;
}

// ---------------- fused transpose+convert for one layer's 5 weights ----------
__global__ __launch_bounds__(256) void convt_fused(const float* __restrict__ wq,
                                                   const float* __restrict__ wkv,
                                                   const float* __restrict__ wo,
                                                   const float* __restrict__ w1,
                                                   const float* __restrict__ w2,
                                                   u16* __restrict__ wtq,
                                                   u16* __restrict__ wto,
                                                   u16* __restrict__ wt1,
                                                   u16* __restrict__ wt2) {
  const int t = blockIdx.x;
  const float* W; u16* Wt; int K, N, local;
  if (t < 1024)      { W = wq;  Wt = wtq;               K = 1024; N = 1024; local = t; }
  else if (t < 1536) { W = wkv; Wt = wtq + 1024*1024;   K = 1024; N = 512;  local = t - 1024; }
  else if (t < 2560) { W = wo;  Wt = wto;               K = 1024; N = 1024; local = t - 1536; }
  else if (t < 6656) { W = w1;  Wt = wt1;               K = 1024; N = 4096; local = t - 2560; }
  else               { W = w2;  Wt = wt2;               K = 4096; N = 1024; local = t - 6656; }
  const int nk = K >> 5;
  const int k0 = (local % nk) * 32, n0 = (local / nk) * 32;
  __shared__ float tb[32][33];
  const int tx = threadIdx.x & 31, ty = threadIdx.x >> 5;   // ty: 0..7
  #pragma unroll
  for (int i = 0; i < 4; i++)
    tb[ty + i*8][tx] = W[(size_t)(k0 + ty + i*8) * N + n0 + tx];
  __syncthreads();
  #pragma unroll
  for (int i = 0; i < 4; i++)
    Wt[(size_t)(n0 + ty + i*8) * K + k0 + tx] = f2bf(tb[tx][ty + i*8]);
}

// ---------------- RMSNorm: f32 in -> bf16 out ----------------
__global__ __launch_bounds__(256) void rmsnorm_kernel(const float* __restrict__ x,
                                                      const float* __restrict__ w,
                                                      u16* __restrict__ out) {
  const int row = blockIdx.x;
  const int tid = threadIdx.x;
  float4 v = reinterpret_cast<const float4*>(x + (size_t)row * D_)[tid];
  float ss = v.x*v.x + v.y*v.y + v.z*v.z + v.w*v.w;
  #pragma unroll
  for (int off = 32; off > 0; off >>= 1) ss += __shfl_down(ss, off, 64);
  __shared__ float red[4];
  if ((tid & 63) == 0) red[tid >> 6] = ss;
  __syncthreads();
  const float tot = red[0] + red[1] + red[2] + red[3];
  const float rstd = rsqrtf(tot * (1.0f / D_) + 1e-6f);
  float4 wv = reinterpret_cast<const float4*>(w)[tid];
  ushort4 ov;
  ov.x = f2bf(v.x * rstd * wv.x);
  ov.y = f2bf(v.y * rstd * wv.y);
  ov.z = f2bf(v.z * rstd * wv.z);
  ov.w = f2bf(v.w * rstd * wv.w);
  reinterpret_cast<ushort4*>(out + (size_t)row * D_)[tid] = ov;
}

// ---------------- GEMM 128x128, XCD-chunked 1-D grid ----------
// EPI: 0 = bf16 out, 1 = f32 out + residual add
template <int EPI>
__global__ __launch_bounds__(256) void gemm_bt(const u16* __restrict__ A,
                                               const u16* __restrict__ Bt,
                                               const float* __restrict__ res,
                                               u16* __restrict__ Cb,
                                               float* __restrict__ Cf,
                                               int M, int N, int K) {
  __shared__ u16 As[128 * 64];
  __shared__ u16 Bs[128 * 64];
  const int tid = threadIdx.x;
  const int nx = N >> 7;
  const int nwg = nx * (M >> 7);
  const int cpx = nwg >> 3;
  const int bid = blockIdx.x;
  const int wg = (bid & 7) * cpx + (bid >> 3);
  const int n0 = (wg % nx) << 7;
  const int m0 = (wg / nx) << 7;
  const int lane = tid & 63, wave = tid >> 6;
  const int wm = wave >> 1, wn = wave & 1;
  const int l15 = lane & 15, l4 = lane >> 4;
  const int srow = tid >> 3, scol = (tid & 7) * 8;
  const u16* ag = A + (size_t)(m0 + srow) * K + scol;
  const u16* bg = Bt + (size_t)(n0 + srow) * K + scol;
  u16* asd = &As[srow * 64 + scol];
  u16* bsd = &Bs[srow * 64 + scol];
  f32x4 acc[4][4] = {};
  const int nk = K >> 6;
  for (int kt = 0; kt < nk; kt++) {
    const int k0 = kt * 64;
    __syncthreads();
    #pragma unroll
    for (int i = 0; i < 4; i++) gl_lds16(ag + (size_t)i*32*K + k0, asd + i*32*64);
    #pragma unroll
    for (int i = 0; i < 4; i++) gl_lds16(bg + (size_t)i*32*K + k0, bsd + i*32*64);
    __syncthreads();
    #pragma unroll
    for (int s = 0; s < 2; s++) {
      bf16x8 af[4], bfv[4];
      #pragma unroll
      for (int i = 0; i < 4; i++)
        af[i] = *reinterpret_cast<const bf16x8*>(&As[(wm*64 + i*16 + l15)*64 + s*32 + l4*8]);
      #pragma unroll
      for (int j = 0; j < 4; j++)
        bfv[j] = *reinterpret_cast<const bf16x8*>(&Bs[(wn*64 + j*16 + l15)*64 + s*32 + l4*8]);
      #pragma unroll
      for (int i = 0; i < 4; i++)
        #pragma unroll
        for (int j = 0; j < 4; j++)
          acc[i][j] = __builtin_amdgcn_mfma_f32_16x16x32_bf16(bfv[j], af[i], acc[i][j], 0, 0, 0);
    }
  }
  // lane holds: row m = ...+l15, cols n = ...+l4*4+rr (contiguous)
  #pragma unroll
  for (int i = 0; i < 4; i++) {
    const int row = m0 + wm*64 + i*16 + l15;
    #pragma unroll
    for (int j = 0; j < 4; j++) {
      const int colb = n0 + wn*64 + j*16 + l4*4;
      const size_t idx = (size_t)row * N + colb;
      const f32x4 v = acc[i][j];
      if (EPI == 0) {
        ushort4 ov;
        ov.x = f2bf(v[0]); ov.y = f2bf(v[1]); ov.z = f2bf(v[2]); ov.w = f2bf(v[3]);
        *reinterpret_cast<ushort4*>(&Cb[idx]) = ov;
      } else {
        const float4 rv = *reinterpret_cast<const float4*>(&res[idx]);
        float4 ov;
        ov.x = v[0] + rv.x; ov.y = v[1] + rv.y; ov.z = v[2] + rv.z; ov.w = v[3] + rv.w;
        *reinterpret_cast<float4*>(&Cf[idx]) = ov;
      }
    }
  }
}

// ---------------- persistent GEMM 256x256, 8-phase counted-vmcnt (K=1024) ----
// Grid 256 blocks. Block bid owns tiles {wg0 + 256*s} with wg0 = (bid&7)*32 +
// (bid>>3): m = wg0 % 16 is FIXED (A panel resident for the block's life);
// at any step the active tiles form a contiguous m-fastest window, so the 16
// blocks sharing an n-panel sit on ONE XCD (round-14's measured-good working
// set) -- fixes round-3's L2 thrash while keeping its verified never-drain
// transition: peeled it=7 prefetches the next tile's k-tiles 0/1 (A base
// unchanged, B moves 16 panels); C stores issue with NO wait (next p4's
// VMC(6) drains them, overlapped with p1-p4). 16 k-tiles/tile keeps slot
// parity. EPI: 0 = f32 out (logits), 1 = exact GELU -> bf16
template <int EPI>
__global__ __launch_bounds__(512, 2) void gemm256p(const u16* __restrict__ A,
                                                   const u16* __restrict__ Bt,
                                                   u16* __restrict__ Cb,
                                                   float* __restrict__ Cf,
                                                   int M, int N) {
  const int K = 1024;
  __shared__ char lds[131072];
  char* const AsB = lds;             // A tiles: slot*32768
  char* const BsB = lds + 65536;     // B tiles: slot*32768
  const int tid = threadIdx.x;
  const int lane = tid & 63, wave = tid >> 6;
  const int wm = wave >> 2, wn = wave & 3;
  const int l15 = lane & 15, l4 = lane >> 4;

  const int nm = M >> 8;                  // 16
  const int nt_all = nm * (N >> 8);       // 2000 (lm_head) / 256 (W1)
  const int bid = blockIdx.x;
  const int wg0 = (bid & 7) * 32 + (bid >> 3);   // grid fixed at 256 blocks

  // staging geometry (proven rounds 2-14)
  int soff[2][2], pd[2][2];
  #pragma unroll
  for (int h = 0; h < 2; ++h)
    #pragma unroll
    for (int jj = 0; jj < 2; ++jj) {
      const int row = h*128 + jj*64 + (tid >> 3);
      const int sl  = (tid & 7) ^ (row & 7);
      soff[h][jj] = row * K + sl * 8;             // u16 elements
      pd[h][jj]   = h*16384 + jj*8192 + tid*16;   // bytes
    }
  const int swz = (l15 & 7) << 4;
  const int rb0 = l15*128 + ((l4*16)      ^ swz);
  const int rb1 = l15*128 + ((64 + l4*16) ^ swz);

  #define STA(P,S,H,T) do { const u16* g_ = (P) + (T)*64; char* d_ = AsB + (S)*32768; \
      gl_lds16(g_ + soff[H][0], d_ + pd[H][0]); gl_lds16(g_ + soff[H][1], d_ + pd[H][1]); } while (0)
  #define STB(P,S,H,T) do { const u16* g_ = (P) + (T)*64; char* d_ = BsB + (S)*32768; \
      gl_lds16(g_ + soff[H][0], d_ + pd[H][0]); gl_lds16(g_ + soff[H][1], d_ + pd[H][1]); } while (0)
  #define RDA(S,GI,RB) (*reinterpret_cast<const bf16x8*>(AsB + (S)*32768 + (GI)*2048 + (RB)))
  #define RDB(S,GJ,RB) (*reinterpret_cast<const bf16x8*>(BsB + (S)*32768 + (GJ)*2048 + (RB)))

  f32x4 acc[8][4] = {};
  bf16x8 Ar[4][2], Br[4][2];

  #define RDA03(S) { _Pragma("unroll") for (int i=0;i<4;++i){ Ar[i][0]=RDA(S,i*2+wm,rb0); Ar[i][1]=RDA(S,i*2+wm,rb1);} }
  #define RDA47(S) { _Pragma("unroll") for (int i=0;i<4;++i){ Ar[i][0]=RDA(S,(i+4)*2+wm,rb0); Ar[i][1]=RDA(S,(i+4)*2+wm,rb1);} }
  #define RDB01(S) { _Pragma("unroll") for (int j=0;j<2;++j){ Br[j][0]=RDB(S,j*4+wn,rb0); Br[j][1]=RDB(S,j*4+wn,rb1);} }
  #define RDB23(S) { _Pragma("unroll") for (int j=2;j<4;++j){ Br[j][0]=RDB(S,j*4+wn,rb0); Br[j][1]=RDB(S,j*4+wn,rb1);} }
  #define MFQ(IO,JL) { _Pragma("unroll") for (int i=0;i<4;++i) _Pragma("unroll") for (int jj=0;jj<2;++jj) { \
      acc[(IO)+i][(JL)+jj] = __builtin_amdgcn_mfma_f32_16x16x32_bf16(Br[(JL)+jj][0], Ar[i][0], acc[(IO)+i][(JL)+jj],0,0,0); \
      acc[(IO)+i][(JL)+jj] = __builtin_amdgcn_mfma_f32_16x16x32_bf16(Br[(JL)+jj][1], Ar[i][1], acc[(IO)+i][(JL)+jj],0,0,0); } }

  int tt = wg0;
  const u16* Ac = A + (size_t)((tt % nm) << 8) * K;
  const u16* Bc = Bt + (size_t)((tt / nm) << 8) * K;

  // one-time prologue: tile0 (4 halves) + tile1 minus A-h1 (staged by p1)
  STA(Ac,0,0,0); STA(Ac,0,1,0); STB(Bc,0,0,0); STB(Bc,0,1,0);
  VMC(4);
  STA(Ac,1,0,1); STB(Bc,1,0,1); STB(Bc,1,1,1);
  VMC(6);
  BARRIER();

  while (tt < nt_all) {
    const int tn = tt + 256;
    const bool last = (tn >= nt_all);
    const u16* An = Ac;                    // m fixed: A base unchanged
    const u16* Bn = last ? Bc : (Bt + (size_t)((tn / nm) << 8) * K);
    // iters 0..6: all prefetch targets within current tile (t0+2 <= 14)
    for (int it = 0; it < 7; ++it) {
      const int t0 = it*2, t1 = t0 + 1;
      RDA03(0); RDB01(0); STA(Ac,1,1,t1);
      BARRIER(); LGK0(); PRIO(1); MFQ(0,0); PRIO(0); BARRIER();
      RDB23(0); STA(Ac,0,0,t0+2);
      BARRIER(); LGK0(); PRIO(1); MFQ(0,2); PRIO(0); BARRIER();
      RDA47(0); STB(Bc,0,0,t0+2);
      BARRIER(); LGK0(); PRIO(1); MFQ(4,0); PRIO(0); BARRIER();
      STB(Bc,0,1,t0+2); VMC(6);
      BARRIER(); PRIO(1); MFQ(4,2); PRIO(0); BARRIER();
      RDA03(1); RDB01(1); STA(Ac,0,1,t0+2);
      BARRIER(); LGK0(); PRIO(1); MFQ(0,0); PRIO(0); BARRIER();
      RDB23(1); STA(Ac,1,0,t1+2);
      BARRIER(); LGK0(); PRIO(1); MFQ(0,2); PRIO(0); BARRIER();
      RDA47(1); STB(Bc,1,0,t1+2);
      BARRIER(); LGK0(); PRIO(1); MFQ(4,0); PRIO(0); BARRIER();
      STB(Bc,1,1,t1+2); VMC(6);
      BARRIER(); PRIO(1); MFQ(4,2); PRIO(0); BARRIER();
    }
    // it = 7 (t0=14, t1=15): prefetch NEXT tile's k-tiles 0/1 (or drain)
    {
      RDA03(0); RDB01(0); STA(Ac,1,1,15);
      BARRIER(); LGK0(); PRIO(1); MFQ(0,0); PRIO(0); BARRIER();
      RDB23(0); if (!last) STA(An,0,0,0);
      BARRIER(); LGK0(); PRIO(1); MFQ(0,2); PRIO(0); BARRIER();
      RDA47(0); if (!last) STB(Bn,0,0,0);
      BARRIER(); LGK0(); PRIO(1); MFQ(4,0); PRIO(0); BARRIER();
      if (!last) { STB(Bn,0,1,0); VMC(6); } else { VMC(0); }
      BARRIER(); PRIO(1); MFQ(4,2); PRIO(0); BARRIER();
      RDA03(1); RDB01(1); if (!last) STA(An,0,1,0);
      BARRIER(); LGK0(); PRIO(1); MFQ(0,0); PRIO(0); BARRIER();
      RDB23(1); if (!last) STA(An,1,0,1);
      BARRIER(); LGK0(); PRIO(1); MFQ(0,2); PRIO(0); BARRIER();
      RDA47(1); if (!last) STB(Bn,1,0,1);
      BARRIER(); LGK0(); PRIO(1); MFQ(4,0); PRIO(0); BARRIER();
      if (!last) { STB(Bn,1,1,1); VMC(6); }
      BARRIER(); PRIO(1); MFQ(4,2); PRIO(0); BARRIER();
    }
    // C write for tile tt (no wait; next p4's VMC(6) drains the stores).
    // lane = row m (l15), 4 contiguous n (l4*4+rr)
    {
      const int m0 = (tt % nm) << 8;
      const int n0 = (tt / nm) << 8;
      #pragma unroll
      for (int i = 0; i < 8; ++i) {
        const int row = m0 + (i*2 + wm)*16 + l15;
        #pragma unroll
        for (int j = 0; j < 4; ++j) {
          const int colb = n0 + (j*4 + wn)*16 + l4*4;
          const f32x4 v = acc[i][j];
          if (EPI == 0) {
            *reinterpret_cast<f32x4*>(&Cf[(size_t)row * N + colb]) = v;
          } else {
            ushort4 ov;
            #pragma unroll
            for (int rr = 0; rr < 4; ++rr) {
              const float g = 0.5f * v[rr] * (1.0f + erff(v[rr] * 0.70710678118f));
              ((u16*)&ov)[rr] = f2bf(g);
            }
            *reinterpret_cast<ushort4*>(&Cb[(size_t)row * N + colb]) = ov;
          }
          acc[i][j] = f32x4{0.f, 0.f, 0.f, 0.f};
        }
      }
    }
    Ac = An; Bc = Bn; tt = tn;
  }
  #undef STA
  #undef STB
  #undef RDA
  #undef RDB
  #undef RDA03
  #undef RDA47
  #undef RDB01
  #undef RDB23
  #undef MFQ
}

// ---------------- flash attention (causal, GQA), qt-paired, 1 barrier/iter ---
// (byte-identical to rounds 12-14 — verified)
__global__ __launch_bounds__(512) void attn_kernel(const u16* __restrict__ qkv,
                                                   u16* __restrict__ o) {
  const int qtA = blockIdx.x;          // 0..7
  const int qtB = 15 - qtA;            // 8..15
  const int h  = blockIdx.y;
  const int b  = blockIdx.z;
  const int kh = h / (H_ / KH_);
  __shared__ u16 Ks[2][64 * 64];
  __shared__ u16 Vt[2][64 * 66];       // V^T [d][k], stride 66, double-buffered
  __shared__ u16 Pl[16][16 * 68];      // P [q][k]; [wave]=tile A, [wave+8]=B
  const int tid = threadIdx.x, lane = tid & 63, wave = tid >> 6;
  const int l15 = lane & 15, l4 = lane >> 4;
  const size_t Mrow = (size_t)b * T_;

  bf16x8 qfA[2], qfB[2];
  {
    const u16* qpA = qkv + (Mrow + qtA*128 + wave*16 + l15) * QKVN + h*HD_ + l4*8;
    const u16* qpB = qkv + (Mrow + qtB*128 + wave*16 + l15) * QKVN + h*HD_ + l4*8;
    qfA[0] = *reinterpret_cast<const bf16x8*>(qpA);
    qfA[1] = *reinterpret_cast<const bf16x8*>(qpA + 32);
    qfB[0] = *reinterpret_cast<const bf16x8*>(qpB);
    qfB[1] = *reinterpret_cast<const bf16x8*>(qpB + 32);
    #pragma unroll
    for (int s = 0; s < 2; s++)
      #pragma unroll
      for (int j = 0; j < 8; j++) {
        qfA[s][j] = (short)f2bf(bf2f((u16)qfA[s][j]) * 0.18033688f);  // 0.125*log2e
        qfB[s][j] = (short)f2bf(bf2f((u16)qfB[s][j]) * 0.18033688f);
      }
  }
  float mA = -1e30f, lA = 0.0f, mB = -1e30f, lB = 0.0f;
  f32x4 oaccA[4] = {}, oaccB[4] = {};

  const int srow = tid >> 3, scol = (tid & 7) * 8;   // K staging: 1 gl_lds/thread
  const int vp = (tid >> 4) * 2;          // V row pair: 0,2,..,62
  const int vd = (tid & 15) * 4;          // V col quad
  const u16* const kbase = qkv + Mrow * QKVN + D_ + kh*HD_;
  const u16* const vbase = kbase + KH_*HD_;

  // prologue: stage tile 0 (K -> Ks[0], V -> Vt[0])
  {
    gl_lds16(kbase + (size_t)srow * QKVN + scol, &Ks[0][srow*64 + scol]);
    const u16* vg = vbase + (size_t)vp * QKVN + vd;
    bf16x4 v0 = *reinterpret_cast<const bf16x4*>(vg);
    bf16x4 v1 = *reinterpret_cast<const bf16x4*>(vg + QKVN);
    #pragma unroll
    for (int j = 0; j < 4; j++) {
      const u32 pk = (u32)(u16)v0[j] | ((u32)(u16)v1[j] << 16);
      *reinterpret_cast<u32*>(&Vt[0][(vd + j)*66 + vp]) = pk;
    }
  }
  __syncthreads();                        // K gl_lds + Vt[0] writes visible

  const int nktA = 2*qtA + 2;
  const int nktB = 2*qtB + 2;             // > nktA always (qtA <= 7)
  for (int kt = 0; kt < nktB; kt++) {
    const int cur = kt & 1;
    const bool pf = kt + 1 < nktB;
    bf16x4 v0n, v1n;
    if (pf) {                             // issue next tile's loads EARLY
      gl_lds16(kbase + (size_t)((kt+1)*64 + srow) * QKVN + scol,
               &Ks[1-cur][srow*64 + scol]);
      const u16* vg = vbase + (size_t)((kt+1)*64 + vp) * QKVN + vd;
      v0n = *reinterpret_cast<const bf16x4*>(vg);
      v1n = *reinterpret_cast<const bf16x4*>(vg + QKVN);
    }

    // ---- tile B QK^T + softmax ----
    f32x4 saB[4] = {};
    #pragma unroll
    for (int s = 0; s < 2; s++)
      #pragma unroll
      for (int n = 0; n < 4; n++) {
        bf16x8 kf = *reinterpret_cast<const bf16x8*>(&Ks[cur][(n*16 + l15)*64 + s*32 + l4*8]);
        saB[n] = __builtin_amdgcn_mfma_f32_16x16x32_bf16(kf, qfB[s], saB[n], 0, 0, 0);
      }
    if (kt >= 2*qtB) {
      const int qloc = wave*16 + l15;
      const int kb = kt*64 - qtB*128 + l4*4;
      #pragma unroll
      for (int n = 0; n < 4; n++)
        #pragma unroll
        for (int r = 0; r < 4; r++)
          if (kb + n*16 + r > qloc) saB[n][r] = -1e30f;
    }
    {
      float mx;
      {
        f32x4 m4;
        #pragma unroll
        for (int r = 0; r < 4; r++)
          m4[r] = fmaxf(fmaxf(saB[0][r], saB[1][r]), fmaxf(saB[2][r], saB[3][r]));
        mx = fmaxf(fmaxf(m4[0], m4[1]), fmaxf(m4[2], m4[3]));
        mx = fmaxf(mx, __shfl_xor(mx, 16, 64));
        mx = fmaxf(mx, __shfl_xor(mx, 32, 64));
      }
      if (__any((int)(mx - mB > 8.0f))) {
        const float nm = fmaxf(mB, mx);
        const float alpha = exp2f(mB - nm);
        mB = nm; lB *= alpha;
        #pragma unroll
        for (int r = 0; r < 4; r++) {
          const float a_r = __shfl(alpha, l4*4 + r, 64);
          #pragma unroll
          for (int n = 0; n < 4; n++) oaccB[n][r] *= a_r;
        }
      }
      float rs = 0.0f;
      u16* pw = &Pl[8 + wave][0];
      #pragma unroll
      for (int n = 0; n < 4; n++) {
        ushort4 pv;
        #pragma unroll
        for (int r = 0; r < 4; r++) {
          const float p = exp2f(saB[n][r] - mB);
          rs += p;
          ((u16*)&pv)[r] = f2bf(p);
        }
        *reinterpret_cast<ushort4*>(&pw[l15*68 + n*16 + l4*4]) = pv;
      }
      rs += __shfl_xor(rs, 16, 64);
      rs += __shfl_xor(rs, 32, 64);
      lB += rs;
    }

    // write V(kt+1) -> Vt[1-cur]: vmcnt wait hides under B's QK^T/softmax;
    // PV below reads Vt[cur] (other buffer) -> no barrier needed in between.
    if (pf) {
      #pragma unroll
      for (int j = 0; j < 4; j++) {
        const u32 pk = (u32)(u16)v0n[j] | ((u32)(u16)v1n[j] << 16);
        *reinterpret_cast<u32*>(&Vt[1-cur][(vd + j)*66 + vp]) = pk;
      }
    }

    asm volatile("s_waitcnt lgkmcnt(0)" ::: "memory");  // P + Vt writes done (in-wave)
    // ---- tile B PV ----
    #pragma unroll
    for (int s = 0; s < 2; s++) {
      bf16x8 pa = *reinterpret_cast<const bf16x8*>(&Pl[8 + wave][l15*68 + s*32 + l4*8]);
      #pragma unroll
      for (int n = 0; n < 4; n++) {
        bf16x8 vb = *reinterpret_cast<const bf16x8*>(&Vt[cur][(n*16 + l15)*66 + s*32 + l4*8]);
        oaccB[n] = __builtin_amdgcn_mfma_f32_16x16x32_bf16(pa, vb, oaccB[n], 0, 0, 0);
      }
    }

    // ---- tile A (active while kt < nktA) ----
    if (kt < nktA) {
      f32x4 sa[4] = {};
      #pragma unroll
      for (int s = 0; s < 2; s++)
        #pragma unroll
        for (int n = 0; n < 4; n++) {
          bf16x8 kf = *reinterpret_cast<const bf16x8*>(&Ks[cur][(n*16 + l15)*64 + s*32 + l4*8]);
          sa[n] = __builtin_amdgcn_mfma_f32_16x16x32_bf16(kf, qfA[s], sa[n], 0, 0, 0);
        }
      if (kt >= 2*qtA) {
        const int qloc = wave*16 + l15;
        const int kb = kt*64 - qtA*128 + l4*4;
        #pragma unroll
        for (int n = 0; n < 4; n++)
          #pragma unroll
          for (int r = 0; r < 4; r++)
            if (kb + n*16 + r > qloc) sa[n][r] = -1e30f;
      }
      float mx;
      {
        f32x4 m4;
        #pragma unroll
        for (int r = 0; r < 4; r++)
          m4[r] = fmaxf(fmaxf(sa[0][r], sa[1][r]), fmaxf(sa[2][r], sa[3][r]));
        mx = fmaxf(fmaxf(m4[0], m4[1]), fmaxf(m4[2], m4[3]));
        mx = fmaxf(mx, __shfl_xor(mx, 16, 64));
        mx = fmaxf(mx, __shfl_xor(mx, 32, 64));
      }
      if (__any((int)(mx - mA > 8.0f))) {
        const float nm = fmaxf(mA, mx);
        const float alpha = exp2f(mA - nm);
        mA = nm; lA *= alpha;
        #pragma unroll
        for (int r = 0; r < 4; r++) {
          const float a_r = __shfl(alpha, l4*4 + r, 64);
          #pragma unroll
          for (int n = 0; n < 4; n++) oaccA[n][r] *= a_r;
        }
      }
      float rs = 0.0f;
      u16* pw = &Pl[wave][0];
      #pragma unroll
      for (int n = 0; n < 4; n++) {
        ushort4 pv;
        #pragma unroll
        for (int r = 0; r < 4; r++) {
          const float p = exp2f(sa[n][r] - mA);
          rs += p;
          ((u16*)&pv)[r] = f2bf(p);
        }
        *reinterpret_cast<ushort4*>(&pw[l15*68 + n*16 + l4*4]) = pv;
      }
      rs += __shfl_xor(rs, 16, 64);
      rs += __shfl_xor(rs, 32, 64);
      lA += rs;
      asm volatile("s_waitcnt lgkmcnt(0)" ::: "memory");
      #pragma unroll
      for (int s = 0; s < 2; s++) {
        bf16x8 pa = *reinterpret_cast<const bf16x8*>(&pw[l15*68 + s*32 + l4*8]);
        #pragma unroll
        for (int n = 0; n < 4; n++) {
          bf16x8 vb = *reinterpret_cast<const bf16x8*>(&Vt[cur][(n*16 + l15)*66 + s*32 + l4*8]);
          oaccA[n] = __builtin_amdgcn_mfma_f32_16x16x32_bf16(pa, vb, oaccA[n], 0, 0, 0);
        }
      }
    }

    __syncthreads();   // Ks[1-cur] staged + Vt[1-cur] writes visible; PV reads done
  }
  // epilogue: normalize + store both tiles
  {
    float lr[4];
    #pragma unroll
    for (int r = 0; r < 4; r++) lr[r] = __shfl(lA, l4*4 + r, 64);
    #pragma unroll
    for (int n = 0; n < 4; n++)
      #pragma unroll
      for (int r = 0; r < 4; r++) {
        const float ov = oaccA[n][r] / lr[r];
        const size_t row = Mrow + qtA*128 + wave*16 + l4*4 + r;
        o[row * (size_t)(H_*HD_) + h*HD_ + n*16 + l15] = f2bf(ov);
      }
    #pragma unroll
    for (int r = 0; r < 4; r++) lr[r] = __shfl(lB, l4*4 + r, 64);
    #pragma unroll
    for (int n = 0; n < 4; n++)
      #pragma unroll
      for (int r = 0; r < 4; r++) {
        const float ov = oaccB[n][r] / lr[r];
        const size_t row = Mrow + qtB*128 + wave*16 + l4*4 + r;
        o[row * (size_t)(H_*HD_) + h*HD_ + n*16 + l15] = f2bf(ov);
      }
  }
}

// ---------------- workspace layout ----------------
#define OFF_X     0ull
#define OFF_H     16777216ull
#define OFF_QKV   25165824ull
#define OFF_O     37748736ull
#define OFF_U     46137344ull
#define OFF_WTQ   79691776ull
#define OFF_WTO   82837504ull
#define OFF_WT1   84934656ull
#define OFF_WT2   93323264ull
#define OFF_EBF   101711872ull

extern "C" void kernel_launch(void* const* d_in, const int* in_sizes, int n_in,
                              void* d_out, int out_size, void* d_ws, size_t ws_size,
                              hipStream_t stream) {
  const int*   ids = (const int*)  d_in[0];
  const float* ew  = (const float*)d_in[1];
  const float* pw  = (const float*)d_in[2];
  const float* ln1 = (const float*)d_in[3];
  const float* ln2 = (const float*)d_in[4];
  const float* wq  = (const float*)d_in[5];
  const float* wkv = (const float*)d_in[6];
  const float* wo  = (const float*)d_in[7];
  const float* w1  = (const float*)d_in[8];
  const float* w2  = (const float*)d_in[9];
  const float* nw  = (const float*)d_in[10];
  float* out = (float*)d_out;

  char* ws = (char*)d_ws;
  float* x   = (float*)(ws + OFF_X);
  u16*   h   = (u16*)  (ws + OFF_H);
  u16*   qkv = (u16*)  (ws + OFF_QKV);
  u16*   o   = (u16*)  (ws + OFF_O);
  u16*   u   = (u16*)  (ws + OFF_U);
  u16*   wtq = (u16*)  (ws + OFF_WTQ);
  u16*   wto = (u16*)  (ws + OFF_WTO);
  u16*   wt1 = (u16*)  (ws + OFF_WT1);
  u16*   wt2 = (u16*)  (ws + OFF_WT2);
  u16*   ebf = (u16*)  (ws + OFF_EBF);

  embed_kernel<<<M_, 256, 0, stream>>>(ids, ew, pw, x);
  conv_kernel<<<(V_*D_/4)/256, 256, 0, stream>>>(ew, ebf);

  for (int l = 0; l < L_; l++) {
    convt_fused<<<10752, 256, 0, stream>>>(
        wq  + (size_t)l*D_*(H_*HD_),
        wkv + (size_t)l*D_*(2*KH_*HD_),
        wo  + (size_t)l*(H_*HD_)*D_,
        w1  + (size_t)l*D_*F_,
        w2  + (size_t)l*F_*D_,
        wtq, wto, wt1, wt2);

    rmsnorm_kernel<<<M_, 256, 0, stream>>>(x, ln1 + (size_t)l*D_, h);
    gemm_bt<0><<<(QKVN/128)*(M_/128), 256, 0, stream>>>(h, wtq, nullptr, qkv, nullptr, M_, QKVN, D_);
    attn_kernel<<<dim3(T_/256, H_, B_), 512, 0, stream>>>(qkv, o);
    gemm_bt<1><<<(D_/128)*(M_/128), 256, 0, stream>>>(o, wto, x, nullptr, x, M_, D_, H_*HD_);
    rmsnorm_kernel<<<M_, 256, 0, stream>>>(x, ln2 + (size_t)l*D_, h);
    gemm256p<1><<<256, 512, 0, stream>>>(h, wt1, u, nullptr, M_, F_);
    gemm_bt<1><<<(D_/128)*(M_/128), 256, 0, stream>>>(u, wt2, x, nullptr, x, M_, D_, F_);
  }

  rmsnorm_kernel<<<M_, 256, 0, stream>>>(x, nw, h);
  gemm256p<0><<<256, 512, 0, stream>>>(h, ebf, nullptr, out, M_, V_);
}

// Round 16
// 1467.371 us; speedup vs baseline: 1.0217x; 1.0217x over previous
//
#include <hip/hip_runtime.h>
#include <hip/hip_bf16.h>

#define DI __device__ __forceinline__

typedef unsigned short u16;
typedef unsigned int u32;
typedef __attribute__((ext_vector_type(8))) short bf16x8;   // 8 bf16 in 4 VGPRs
typedef __attribute__((ext_vector_type(4))) short bf16x4;   // 4 bf16 in 2 VGPRs
typedef __attribute__((ext_vector_type(4))) float f32x4;

// ---- model constants ----
#define B_   2
#define T_   2048
#define D_   1024
#define H_   16
#define KH_  4
#define HD_  64
#define F_   4096
#define L_   4
#define V_   32000
#define M_   (B_ * T_)          // 4096 tokens
#define QKVN (H_*HD_ + 2*KH_*HD_)  // 1536

DI u16 f2bf(float f) {
  __hip_bfloat16 h = __float2bfloat16(f);
  return *reinterpret_cast<u16*>(&h);
}

DI float bf2f(u16 b) {
  __hip_bfloat16 h = *reinterpret_cast<__hip_bfloat16*>(&b);
  return __bfloat162float(h);
}

DI void gl_lds16(const void* g, void* l) {
  __builtin_amdgcn_global_load_lds(
      (const __attribute__((address_space(1))) u32*)g,
      (__attribute__((address_space(3))) u32*)l, 16, 0, 0);
}

#define BARRIER() do { asm volatile("" ::: "memory"); __builtin_amdgcn_s_barrier(); asm volatile("" ::: "memory"); } while (0)
#define LGK0()    asm volatile("s_waitcnt lgkmcnt(0)" ::: "memory")
#define VMC(n)    asm volatile("s_waitcnt vmcnt(" #n ")" ::: "memory")
#define PRIO(p)   __builtin_amdgcn_s_setprio(p)

// ---------------- embedding: x = embed[ids] + pos ----------------
__global__ __launch_bounds__(256) void embed_kernel(const int* __restrict__ ids,
                                                    const float* __restrict__ ew,
                                                    const float* __restrict__ pw,
                                                    float* __restrict__ x) {
  const int row = blockIdx.x;          // 0..4095
  const int t = row & (T_ - 1);
  const int id = ids[row];
  float4 e = reinterpret_cast<const float4*>(ew + (size_t)id * D_)[threadIdx.x];
  float4 p = reinterpret_cast<const float4*>(pw + (size_t)t * D_)[threadIdx.x];
  e.x += p.x; e.y += p.y; e.z += p.z; e.w += p.w;
  reinterpret_cast<float4*>(x + (size_t)row * D_)[threadIdx.x] = e;
}

// ---------------- f32 -> bf16 elementwise (embed table) ----------------
__global__ __launch_bounds__(256) void conv_kernel(const float* __restrict__ W,
                                                   u16* __restrict__ Wb) {
  const size_t i = (size_t)blockIdx.x * 256 + threadIdx.x;   // float4 index
  float4 v = reinterpret_cast<const float4*>(W)[i];
  ushort4 ov;
  ov.x = f2bf(v.x); ov.y = f2bf(v.y); ov.z = f2bf(v.z); ov.w = f2bf(v.w);
  reinterpret_cast<ushort4*>(Wb)[i] = ov;
}

// ---------------- fused transpose+convert for one layer's 5 weights ----------
__global__ __launch_bounds__(256) void convt_fused(const float* __restrict__ wq,
                                                   const float* __restrict__ wkv,
                                                   const float* __restrict__ wo,
                                                   const float* __restrict__ w1,
                                                   const float* __restrict__ w2,
                                                   u16* __restrict__ wtq,
                                                   u16* __restrict__ wto,
                                                   u16* __restrict__ wt1,
                                                   u16* __restrict__ wt2) {
  const int t = blockIdx.x;
  const float* W; u16* Wt; int K, N, local;
  if (t < 1024)      { W = wq;  Wt = wtq;               K = 1024; N = 1024; local = t; }
  else if (t < 1536) { W = wkv; Wt = wtq + 1024*1024;   K = 1024; N = 512;  local = t - 1024; }
  else if (t < 2560) { W = wo;  Wt = wto;               K = 1024; N = 1024; local = t - 1536; }
  else if (t < 6656) { W = w1;  Wt = wt1;               K = 1024; N = 4096; local = t - 2560; }
  else               { W = w2;  Wt = wt2;               K = 4096; N = 1024; local = t - 6656; }
  const int nk = K >> 5;
  const int k0 = (local % nk) * 32, n0 = (local / nk) * 32;
  __shared__ float tb[32][33];
  const int tx = threadIdx.x & 31, ty = threadIdx.x >> 5;   // ty: 0..7
  #pragma unroll
  for (int i = 0; i < 4; i++)
    tb[ty + i*8][tx] = W[(size_t)(k0 + ty + i*8) * N + n0 + tx];
  __syncthreads();
  #pragma unroll
  for (int i = 0; i < 4; i++)
    Wt[(size_t)(n0 + ty + i*8) * K + k0 + tx] = f2bf(tb[tx][ty + i*8]);
}

// ---------------- RMSNorm: f32 in -> bf16 out ----------------
__global__ __launch_bounds__(256) void rmsnorm_kernel(const float* __restrict__ x,
                                                      const float* __restrict__ w,
                                                      u16* __restrict__ out) {
  const int row = blockIdx.x;
  const int tid = threadIdx.x;
  float4 v = reinterpret_cast<const float4*>(x + (size_t)row * D_)[tid];
  float ss = v.x*v.x + v.y*v.y + v.z*v.z + v.w*v.w;
  #pragma unroll
  for (int off = 32; off > 0; off >>= 1) ss += __shfl_down(ss, off, 64);
  __shared__ float red[4];
  if ((tid & 63) == 0) red[tid >> 6] = ss;
  __syncthreads();
  const float tot = red[0] + red[1] + red[2] + red[3];
  const float rstd = rsqrtf(tot * (1.0f / D_) + 1e-6f);
  float4 wv = reinterpret_cast<const float4*>(w)[tid];
  ushort4 ov;
  ov.x = f2bf(v.x * rstd * wv.x);
  ov.y = f2bf(v.y * rstd * wv.y);
  ov.z = f2bf(v.z * rstd * wv.z);
  ov.w = f2bf(v.w * rstd * wv.w);
  reinterpret_cast<ushort4*>(out + (size_t)row * D_)[tid] = ov;
}

// ---------------- GEMM 128x128, XCD-chunked 1-D grid ----------
// EPI: 0 = bf16 out, 1 = f32 out + residual add
template <int EPI>
__global__ __launch_bounds__(256) void gemm_bt(const u16* __restrict__ A,
                                               const u16* __restrict__ Bt,
                                               const float* __restrict__ res,
                                               u16* __restrict__ Cb,
                                               float* __restrict__ Cf,
                                               int M, int N, int K) {
  __shared__ u16 As[128 * 64];
  __shared__ u16 Bs[128 * 64];
  const int tid = threadIdx.x;
  const int nx = N >> 7;
  const int nwg = nx * (M >> 7);
  const int cpx = nwg >> 3;
  const int bid = blockIdx.x;
  const int wg = (bid & 7) * cpx + (bid >> 3);
  const int n0 = (wg % nx) << 7;
  const int m0 = (wg / nx) << 7;
  const int lane = tid & 63, wave = tid >> 6;
  const int wm = wave >> 1, wn = wave & 1;
  const int l15 = lane & 15, l4 = lane >> 4;
  const int srow = tid >> 3, scol = (tid & 7) * 8;
  const u16* ag = A + (size_t)(m0 + srow) * K + scol;
  const u16* bg = Bt + (size_t)(n0 + srow) * K + scol;
  u16* asd = &As[srow * 64 + scol];
  u16* bsd = &Bs[srow * 64 + scol];
  f32x4 acc[4][4] = {};
  const int nk = K >> 6;
  for (int kt = 0; kt < nk; kt++) {
    const int k0 = kt * 64;
    __syncthreads();
    #pragma unroll
    for (int i = 0; i < 4; i++) gl_lds16(ag + (size_t)i*32*K + k0, asd + i*32*64);
    #pragma unroll
    for (int i = 0; i < 4; i++) gl_lds16(bg + (size_t)i*32*K + k0, bsd + i*32*64);
    __syncthreads();
    #pragma unroll
    for (int s = 0; s < 2; s++) {
      bf16x8 af[4], bfv[4];
      #pragma unroll
      for (int i = 0; i < 4; i++)
        af[i] = *reinterpret_cast<const bf16x8*>(&As[(wm*64 + i*16 + l15)*64 + s*32 + l4*8]);
      #pragma unroll
      for (int j = 0; j < 4; j++)
        bfv[j] = *reinterpret_cast<const bf16x8*>(&Bs[(wn*64 + j*16 + l15)*64 + s*32 + l4*8]);
      #pragma unroll
      for (int i = 0; i < 4; i++)
        #pragma unroll
        for (int j = 0; j < 4; j++)
          acc[i][j] = __builtin_amdgcn_mfma_f32_16x16x32_bf16(bfv[j], af[i], acc[i][j], 0, 0, 0);
    }
  }
  // lane holds: row m = ...+l15, cols n = ...+l4*4+rr (contiguous)
  #pragma unroll
  for (int i = 0; i < 4; i++) {
    const int row = m0 + wm*64 + i*16 + l15;
    #pragma unroll
    for (int j = 0; j < 4; j++) {
      const int colb = n0 + wn*64 + j*16 + l4*4;
      const size_t idx = (size_t)row * N + colb;
      const f32x4 v = acc[i][j];
      if (EPI == 0) {
        ushort4 ov;
        ov.x = f2bf(v[0]); ov.y = f2bf(v[1]); ov.z = f2bf(v[2]); ov.w = f2bf(v[3]);
        *reinterpret_cast<ushort4*>(&Cb[idx]) = ov;
      } else {
        const float4 rv = *reinterpret_cast<const float4*>(&res[idx]);
        float4 ov;
        ov.x = v[0] + rv.x; ov.y = v[1] + rv.y; ov.z = v[2] + rv.z; ov.w = v[3] + rv.w;
        *reinterpret_cast<float4*>(&Cf[idx]) = ov;
      }
    }
  }
}

// ---------------- GEMM 256x256, 8-phase counted-vmcnt, TAIL-INTERLEAVED C ----
// Non-persistent (measured best across 4 structural attempts). Last K-iter
// peeled; each accumulator quadrant stored right after the phase completing
// it. EPI: 0 = f32 out (logits), 1 = exact GELU -> bf16
template <int EPI>
__global__ __launch_bounds__(512, 2) void gemm256(const u16* __restrict__ A,
                                                  const u16* __restrict__ Bt,
                                                  u16* __restrict__ Cb,
                                                  float* __restrict__ Cf,
                                                  int M, int N, int K) {
  __shared__ char lds[131072];
  char* const AsB = lds;             // A tiles: slot*32768
  char* const BsB = lds + 65536;     // B tiles: slot*32768
  const int tid = threadIdx.x;
  const int lane = tid & 63, wave = tid >> 6;
  const int wm = wave >> 2, wn = wave & 3;
  const int l15 = lane & 15, l4 = lane >> 4;

  // XCD-chunked, m-fastest block decode (nwg % 8 == 0 for all our shapes)
  const int nm = M >> 8;
  const int nwg = nm * (N >> 8);
  const int cpx = nwg >> 3;
  const int bid = blockIdx.x;
  const int wg = (bid & 7) * cpx + (bid >> 3);
  const int m0 = (wg % nm) << 8;
  const int n0 = (wg / nm) << 8;

  const u16* const Atile = A + (size_t)m0 * K;
  const u16* const Btile = Bt + (size_t)n0 * K;

  // staging geometry (proven rounds 2-13)
  int soff[2][2], pd[2][2];
  #pragma unroll
  for (int h = 0; h < 2; ++h)
    #pragma unroll
    for (int jj = 0; jj < 2; ++jj) {
      const int row = h*128 + jj*64 + (tid >> 3);
      const int sl  = (tid & 7) ^ (row & 7);
      soff[h][jj] = row * K + sl * 8;             // u16 elements
      pd[h][jj]   = h*16384 + jj*8192 + tid*16;   // bytes
    }
  const int swz = (l15 & 7) << 4;
  const int rb0 = l15*128 + ((l4*16)      ^ swz);
  const int rb1 = l15*128 + ((64 + l4*16) ^ swz);

  #define STA(S,H,T) do { const u16* g_ = Atile + (T)*64; char* d_ = AsB + (S)*32768; \
      gl_lds16(g_ + soff[H][0], d_ + pd[H][0]); gl_lds16(g_ + soff[H][1], d_ + pd[H][1]); } while (0)
  #define STB(S,H,T) do { const u16* g_ = Btile + (T)*64; char* d_ = BsB + (S)*32768; \
      gl_lds16(g_ + soff[H][0], d_ + pd[H][0]); gl_lds16(g_ + soff[H][1], d_ + pd[H][1]); } while (0)
  #define RDA(S,GI,RB) (*reinterpret_cast<const bf16x8*>(AsB + (S)*32768 + (GI)*2048 + (RB)))
  #define RDB(S,GJ,RB) (*reinterpret_cast<const bf16x8*>(BsB + (S)*32768 + (GJ)*2048 + (RB)))

  f32x4 acc[8][4] = {};
  bf16x8 Ar[4][2], Br[4][2];

  #define RDA03(S) { _Pragma("unroll") for (int i=0;i<4;++i){ Ar[i][0]=RDA(S,i*2+wm,rb0); Ar[i][1]=RDA(S,i*2+wm,rb1);} }
  #define RDA47(S) { _Pragma("unroll") for (int i=0;i<4;++i){ Ar[i][0]=RDA(S,(i+4)*2+wm,rb0); Ar[i][1]=RDA(S,(i+4)*2+wm,rb1);} }
  #define RDB01(S) { _Pragma("unroll") for (int j=0;j<2;++j){ Br[j][0]=RDB(S,j*4+wn,rb0); Br[j][1]=RDB(S,j*4+wn,rb1);} }
  #define RDB23(S) { _Pragma("unroll") for (int j=2;j<4;++j){ Br[j][0]=RDB(S,j*4+wn,rb0); Br[j][1]=RDB(S,j*4+wn,rb1);} }
  #define MFQ(IO,JL) { _Pragma("unroll") for (int i=0;i<4;++i) _Pragma("unroll") for (int jj=0;jj<2;++jj) { \
      acc[(IO)+i][(JL)+jj] = __builtin_amdgcn_mfma_f32_16x16x32_bf16(Br[(JL)+jj][0], Ar[i][0], acc[(IO)+i][(JL)+jj],0,0,0); \
      acc[(IO)+i][(JL)+jj] = __builtin_amdgcn_mfma_f32_16x16x32_bf16(Br[(JL)+jj][1], Ar[i][1], acc[(IO)+i][(JL)+jj],0,0,0); } }
  // quadrant C-write: rows i in [I0,I1), col-groups j in [J0,J1)
  #define EPIW(I0,I1,J0,J1) { _Pragma("unroll") for (int i=(I0);i<(I1);++i){ \
      const int row_ = m0 + (i*2 + wm)*16 + l15; \
      _Pragma("unroll") for (int j=(J0);j<(J1);++j){ \
        const int colb_ = n0 + (j*4 + wn)*16 + l4*4; \
        const f32x4 v_ = acc[i][j]; \
        if (EPI == 0) { \
          *reinterpret_cast<f32x4*>(&Cf[(size_t)row_ * N + colb_]) = v_; \
        } else { \
          ushort4 ov_; \
          _Pragma("unroll") for (int rr=0;rr<4;++rr){ \
            const float g_ = 0.5f * v_[rr] * (1.0f + erff(v_[rr] * 0.70710678118f)); \
            ((u16*)&ov_)[rr] = f2bf(g_); } \
          *reinterpret_cast<ushort4*>(&Cb[(size_t)row_ * N + colb_]) = ov_; \
        } } } }

  // prologue: tile0 (4 halves) + tile1 minus A-h1 (staged by p1 of iter 0)
  STA(0,0,0); STA(0,1,0); STB(0,0,0); STB(0,1,0);
  VMC(4);
  STA(1,0,1); STB(1,0,1); STB(1,1,1);
  VMC(6);
  BARRIER();

  const int niter = K >> 7;    // 2 K-tiles (BK=64) per iteration
  for (int it = 0; it < niter - 1; ++it) {    // steady state: prefetch always on
    const int t0 = it*2, t1 = t0 + 1;
    RDA03(0); RDB01(0); STA(1,1,t1);
    BARRIER(); LGK0(); PRIO(1); MFQ(0,0); PRIO(0); BARRIER();
    RDB23(0); STA(0,0,t0+2);
    BARRIER(); LGK0(); PRIO(1); MFQ(0,2); PRIO(0); BARRIER();
    RDA47(0); STB(0,0,t0+2);
    BARRIER(); LGK0(); PRIO(1); MFQ(4,0); PRIO(0); BARRIER();
    STB(0,1,t0+2); VMC(6);
    BARRIER(); PRIO(1); MFQ(4,2); PRIO(0); BARRIER();
    RDA03(1); RDB01(1); STA(0,1,t0+2);
    BARRIER(); LGK0(); PRIO(1); MFQ(0,0); PRIO(0); BARRIER();
    RDB23(1); STA(1,0,t1+2);
    BARRIER(); LGK0(); PRIO(1); MFQ(0,2); PRIO(0); BARRIER();
    RDA47(1); STB(1,0,t1+2);
    BARRIER(); LGK0(); PRIO(1); MFQ(4,0); PRIO(0); BARRIER();
    STB(1,1,t1+2); VMC(6);
    BARRIER(); PRIO(1); MFQ(4,2); PRIO(0); BARRIER();
  }
  // peeled tail (tiles 2*niter-2, 2*niter-1): no prefetch; C-writes interleaved
  {
    const int t1 = 2*niter - 1;
    RDA03(0); RDB01(0); STA(1,1,t1);
    BARRIER(); LGK0(); PRIO(1); MFQ(0,0); PRIO(0); BARRIER();
    RDB23(0);
    BARRIER(); LGK0(); PRIO(1); MFQ(0,2); PRIO(0); BARRIER();
    RDA47(0);
    BARRIER(); LGK0(); PRIO(1); MFQ(4,0); PRIO(0); BARRIER();
    VMC(0);
    BARRIER(); PRIO(1); MFQ(4,2); PRIO(0); BARRIER();
    RDA03(1); RDB01(1);
    BARRIER(); LGK0(); PRIO(1); MFQ(0,0); PRIO(0); BARRIER();
    EPIW(0,4,0,2);                        // acc[0..3][0..1] complete
    RDB23(1);
    BARRIER(); LGK0(); PRIO(1); MFQ(0,2); PRIO(0); BARRIER();
    EPIW(0,4,2,4);                        // acc[0..3][2..3] complete
    RDA47(1);
    BARRIER(); LGK0(); PRIO(1); MFQ(4,0); PRIO(0); BARRIER();
    EPIW(4,8,0,2);                        // acc[4..7][0..1] complete
    BARRIER(); PRIO(1); MFQ(4,2); PRIO(0);
    EPIW(4,8,2,4);                        // acc[4..7][2..3] complete
  }
  #undef STA
  #undef STB
  #undef RDA
  #undef RDB
  #undef RDA03
  #undef RDA47
  #undef RDB01
  #undef RDB23
  #undef MFQ
  #undef EPIW
}

// ---------------- flash attention (causal, GQA), qt-paired, 1 barrier/iter ---
// (byte-identical to rounds 12-14 — verified)
__global__ __launch_bounds__(512) void attn_kernel(const u16* __restrict__ qkv,
                                                   u16* __restrict__ o) {
  const int qtA = blockIdx.x;          // 0..7
  const int qtB = 15 - qtA;            // 8..15
  const int h  = blockIdx.y;
  const int b  = blockIdx.z;
  const int kh = h / (H_ / KH_);
  __shared__ u16 Ks[2][64 * 64];
  __shared__ u16 Vt[2][64 * 66];       // V^T [d][k], stride 66, double-buffered
  __shared__ u16 Pl[16][16 * 68];      // P [q][k]; [wave]=tile A, [wave+8]=B
  const int tid = threadIdx.x, lane = tid & 63, wave = tid >> 6;
  const int l15 = lane & 15, l4 = lane >> 4;
  const size_t Mrow = (size_t)b * T_;

  bf16x8 qfA[2], qfB[2];
  {
    const u16* qpA = qkv + (Mrow + qtA*128 + wave*16 + l15) * QKVN + h*HD_ + l4*8;
    const u16* qpB = qkv + (Mrow + qtB*128 + wave*16 + l15) * QKVN + h*HD_ + l4*8;
    qfA[0] = *reinterpret_cast<const bf16x8*>(qpA);
    qfA[1] = *reinterpret_cast<const bf16x8*>(qpA + 32);
    qfB[0] = *reinterpret_cast<const bf16x8*>(qpB);
    qfB[1] = *reinterpret_cast<const bf16x8*>(qpB + 32);
    #pragma unroll
    for (int s = 0; s < 2; s++)
      #pragma unroll
      for (int j = 0; j < 8; j++) {
        qfA[s][j] = (short)f2bf(bf2f((u16)qfA[s][j]) * 0.18033688f);  // 0.125*log2e
        qfB[s][j] = (short)f2bf(bf2f((u16)qfB[s][j]) * 0.18033688f);
      }
  }
  float mA = -1e30f, lA = 0.0f, mB = -1e30f, lB = 0.0f;
  f32x4 oaccA[4] = {}, oaccB[4] = {};

  const int srow = tid >> 3, scol = (tid & 7) * 8;   // K staging: 1 gl_lds/thread
  const int vp = (tid >> 4) * 2;          // V row pair: 0,2,..,62
  const int vd = (tid & 15) * 4;          // V col quad
  const u16* const kbase = qkv + Mrow * QKVN + D_ + kh*HD_;
  const u16* const vbase = kbase + KH_*HD_;

  // prologue: stage tile 0 (K -> Ks[0], V -> Vt[0])
  {
    gl_lds16(kbase + (size_t)srow * QKVN + scol, &Ks[0][srow*64 + scol]);
    const u16* vg = vbase + (size_t)vp * QKVN + vd;
    bf16x4 v0 = *reinterpret_cast<const bf16x4*>(vg);
    bf16x4 v1 = *reinterpret_cast<const bf16x4*>(vg + QKVN);
    #pragma unroll
    for (int j = 0; j < 4; j++) {
      const u32 pk = (u32)(u16)v0[j] | ((u32)(u16)v1[j] << 16);
      *reinterpret_cast<u32*>(&Vt[0][(vd + j)*66 + vp]) = pk;
    }
  }
  __syncthreads();                        // K gl_lds + Vt[0] writes visible

  const int nktA = 2*qtA + 2;
  const int nktB = 2*qtB + 2;             // > nktA always (qtA <= 7)
  for (int kt = 0; kt < nktB; kt++) {
    const int cur = kt & 1;
    const bool pf = kt + 1 < nktB;
    bf16x4 v0n, v1n;
    if (pf) {                             // issue next tile's loads EARLY
      gl_lds16(kbase + (size_t)((kt+1)*64 + srow) * QKVN + scol,
               &Ks[1-cur][srow*64 + scol]);
      const u16* vg = vbase + (size_t)((kt+1)*64 + vp) * QKVN + vd;
      v0n = *reinterpret_cast<const bf16x4*>(vg);
      v1n = *reinterpret_cast<const bf16x4*>(vg + QKVN);
    }

    // ---- tile B QK^T + softmax ----
    f32x4 saB[4] = {};
    #pragma unroll
    for (int s = 0; s < 2; s++)
      #pragma unroll
      for (int n = 0; n < 4; n++) {
        bf16x8 kf = *reinterpret_cast<const bf16x8*>(&Ks[cur][(n*16 + l15)*64 + s*32 + l4*8]);
        saB[n] = __builtin_amdgcn_mfma_f32_16x16x32_bf16(kf, qfB[s], saB[n], 0, 0, 0);
      }
    if (kt >= 2*qtB) {
      const int qloc = wave*16 + l15;
      const int kb = kt*64 - qtB*128 + l4*4;
      #pragma unroll
      for (int n = 0; n < 4; n++)
        #pragma unroll
        for (int r = 0; r < 4; r++)
          if (kb + n*16 + r > qloc) saB[n][r] = -1e30f;
    }
    {
      float mx;
      {
        f32x4 m4;
        #pragma unroll
        for (int r = 0; r < 4; r++)
          m4[r] = fmaxf(fmaxf(saB[0][r], saB[1][r]), fmaxf(saB[2][r], saB[3][r]));
        mx = fmaxf(fmaxf(m4[0], m4[1]), fmaxf(m4[2], m4[3]));
        mx = fmaxf(mx, __shfl_xor(mx, 16, 64));
        mx = fmaxf(mx, __shfl_xor(mx, 32, 64));
      }
      if (__any((int)(mx - mB > 8.0f))) {
        const float nm = fmaxf(mB, mx);
        const float alpha = exp2f(mB - nm);
        mB = nm; lB *= alpha;
        #pragma unroll
        for (int r = 0; r < 4; r++) {
          const float a_r = __shfl(alpha, l4*4 + r, 64);
          #pragma unroll
          for (int n = 0; n < 4; n++) oaccB[n][r] *= a_r;
        }
      }
      float rs = 0.0f;
      u16* pw = &Pl[8 + wave][0];
      #pragma unroll
      for (int n = 0; n < 4; n++) {
        ushort4 pv;
        #pragma unroll
        for (int r = 0; r < 4; r++) {
          const float p = exp2f(saB[n][r] - mB);
          rs += p;
          ((u16*)&pv)[r] = f2bf(p);
        }
        *reinterpret_cast<ushort4*>(&pw[l15*68 + n*16 + l4*4]) = pv;
      }
      rs += __shfl_xor(rs, 16, 64);
      rs += __shfl_xor(rs, 32, 64);
      lB += rs;
    }

    // write V(kt+1) -> Vt[1-cur]: vmcnt wait hides under B's QK^T/softmax;
    // PV below reads Vt[cur] (other buffer) -> no barrier needed in between.
    if (pf) {
      #pragma unroll
      for (int j = 0; j < 4; j++) {
        const u32 pk = (u32)(u16)v0n[j] | ((u32)(u16)v1n[j] << 16);
        *reinterpret_cast<u32*>(&Vt[1-cur][(vd + j)*66 + vp]) = pk;
      }
    }

    asm volatile("s_waitcnt lgkmcnt(0)" ::: "memory");  // P + Vt writes done (in-wave)
    // ---- tile B PV ----
    #pragma unroll
    for (int s = 0; s < 2; s++) {
      bf16x8 pa = *reinterpret_cast<const bf16x8*>(&Pl[8 + wave][l15*68 + s*32 + l4*8]);
      #pragma unroll
      for (int n = 0; n < 4; n++) {
        bf16x8 vb = *reinterpret_cast<const bf16x8*>(&Vt[cur][(n*16 + l15)*66 + s*32 + l4*8]);
        oaccB[n] = __builtin_amdgcn_mfma_f32_16x16x32_bf16(pa, vb, oaccB[n], 0, 0, 0);
      }
    }

    // ---- tile A (active while kt < nktA) ----
    if (kt < nktA) {
      f32x4 sa[4] = {};
      #pragma unroll
      for (int s = 0; s < 2; s++)
        #pragma unroll
        for (int n = 0; n < 4; n++) {
          bf16x8 kf = *reinterpret_cast<const bf16x8*>(&Ks[cur][(n*16 + l15)*64 + s*32 + l4*8]);
          sa[n] = __builtin_amdgcn_mfma_f32_16x16x32_bf16(kf, qfA[s], sa[n], 0, 0, 0);
        }
      if (kt >= 2*qtA) {
        const int qloc = wave*16 + l15;
        const int kb = kt*64 - qtA*128 + l4*4;
        #pragma unroll
        for (int n = 0; n < 4; n++)
          #pragma unroll
          for (int r = 0; r < 4; r++)
            if (kb + n*16 + r > qloc) sa[n][r] = -1e30f;
      }
      float mx;
      {
        f32x4 m4;
        #pragma unroll
        for (int r = 0; r < 4; r++)
          m4[r] = fmaxf(fmaxf(sa[0][r], sa[1][r]), fmaxf(sa[2][r], sa[3][r]));
        mx = fmaxf(fmaxf(m4[0], m4[1]), fmaxf(m4[2], m4[3]));
        mx = fmaxf(mx, __shfl_xor(mx, 16, 64));
        mx = fmaxf(mx, __shfl_xor(mx, 32, 64));
      }
      if (__any((int)(mx - mA > 8.0f))) {
        const float nm = fmaxf(mA, mx);
        const float alpha = exp2f(mA - nm);
        mA = nm; lA *= alpha;
        #pragma unroll
        for (int r = 0; r < 4; r++) {
          const float a_r = __shfl(alpha, l4*4 + r, 64);
          #pragma unroll
          for (int n = 0; n < 4; n++) oaccA[n][r] *= a_r;
        }
      }
      float rs = 0.0f;
      u16* pw = &Pl[wave][0];
      #pragma unroll
      for (int n = 0; n < 4; n++) {
        ushort4 pv;
        #pragma unroll
        for (int r = 0; r < 4; r++) {
          const float p = exp2f(sa[n][r] - mA);
          rs += p;
          ((u16*)&pv)[r] = f2bf(p);
        }
        *reinterpret_cast<ushort4*>(&pw[l15*68 + n*16 + l4*4]) = pv;
      }
      rs += __shfl_xor(rs, 16, 64);
      rs += __shfl_xor(rs, 32, 64);
      lA += rs;
      asm volatile("s_waitcnt lgkmcnt(0)" ::: "memory");
      #pragma unroll
      for (int s = 0; s < 2; s++) {
        bf16x8 pa = *reinterpret_cast<const bf16x8*>(&pw[l15*68 + s*32 + l4*8]);
        #pragma unroll
        for (int n = 0; n < 4; n++) {
          bf16x8 vb = *reinterpret_cast<const bf16x8*>(&Vt[cur][(n*16 + l15)*66 + s*32 + l4*8]);
          oaccA[n] = __builtin_amdgcn_mfma_f32_16x16x32_bf16(pa, vb, oaccA[n], 0, 0, 0);
        }
      }
    }

    __syncthreads();   // Ks[1-cur] staged + Vt[1-cur] writes visible; PV reads done
  }
  // epilogue: normalize + store both tiles
  {
    float lr[4];
    #pragma unroll
    for (int r = 0; r < 4; r++) lr[r] = __shfl(lA, l4*4 + r, 64);
    #pragma unroll
    for (int n = 0; n < 4; n++)
      #pragma unroll
      for (int r = 0; r < 4; r++) {
        const float ov = oaccA[n][r] / lr[r];
        const size_t row = Mrow + qtA*128 + wave*16 + l4*4 + r;
        o[row * (size_t)(H_*HD_) + h*HD_ + n*16 + l15] = f2bf(ov);
      }
    #pragma unroll
    for (int r = 0; r < 4; r++) lr[r] = __shfl(lB, l4*4 + r, 64);
    #pragma unroll
    for (int n = 0; n < 4; n++)
      #pragma unroll
      for (int r = 0; r < 4; r++) {
        const float ov = oaccB[n][r] / lr[r];
        const size_t row = Mrow + qtB*128 + wave*16 + l4*4 + r;
        o[row * (size_t)(H_*HD_) + h*HD_ + n*16 + l15] = f2bf(ov);
      }
  }
}

// ---------------- workspace layout ----------------
#define OFF_X     0ull
#define OFF_H     16777216ull
#define OFF_QKV   25165824ull
#define OFF_O     37748736ull
#define OFF_U     46137344ull
#define OFF_WTQ   79691776ull
#define OFF_WTO   82837504ull
#define OFF_WT1   84934656ull
#define OFF_WT2   93323264ull
#define OFF_EBF   101711872ull

extern "C" void kernel_launch(void* const* d_in, const int* in_sizes, int n_in,
                              void* d_out, int out_size, void* d_ws, size_t ws_size,
                              hipStream_t stream) {
  const int*   ids = (const int*)  d_in[0];
  const float* ew  = (const float*)d_in[1];
  const float* pw  = (const float*)d_in[2];
  const float* ln1 = (const float*)d_in[3];
  const float* ln2 = (const float*)d_in[4];
  const float* wq  = (const float*)d_in[5];
  const float* wkv = (const float*)d_in[6];
  const float* wo  = (const float*)d_in[7];
  const float* w1  = (const float*)d_in[8];
  const float* w2  = (const float*)d_in[9];
  const float* nw  = (const float*)d_in[10];
  float* out = (float*)d_out;

  char* ws = (char*)d_ws;
  float* x   = (float*)(ws + OFF_X);
  u16*   h   = (u16*)  (ws + OFF_H);
  u16*   qkv = (u16*)  (ws + OFF_QKV);
  u16*   o   = (u16*)  (ws + OFF_O);
  u16*   u   = (u16*)  (ws + OFF_U);
  u16*   wtq = (u16*)  (ws + OFF_WTQ);
  u16*   wto = (u16*)  (ws + OFF_WTO);
  u16*   wt1 = (u16*)  (ws + OFF_WT1);
  u16*   wt2 = (u16*)  (ws + OFF_WT2);
  u16*   ebf = (u16*)  (ws + OFF_EBF);

  embed_kernel<<<M_, 256, 0, stream>>>(ids, ew, pw, x);
  conv_kernel<<<(V_*D_/4)/256, 256, 0, stream>>>(ew, ebf);

  for (int l = 0; l < L_; l++) {
    convt_fused<<<10752, 256, 0, stream>>>(
        wq  + (size_t)l*D_*(H_*HD_),
        wkv + (size_t)l*D_*(2*KH_*HD_),
        wo  + (size_t)l*(H_*HD_)*D_,
        w1  + (size_t)l*D_*F_,
        w2  + (size_t)l*F_*D_,
        wtq, wto, wt1, wt2);

    rmsnorm_kernel<<<M_, 256, 0, stream>>>(x, ln1 + (size_t)l*D_, h);
    gemm_bt<0><<<(QKVN/128)*(M_/128), 256, 0, stream>>>(h, wtq, nullptr, qkv, nullptr, M_, QKVN, D_);
    attn_kernel<<<dim3(T_/256, H_, B_), 512, 0, stream>>>(qkv, o);
    gemm_bt<1><<<(D_/128)*(M_/128), 256, 0, stream>>>(o, wto, x, nullptr, x, M_, D_, H_*HD_);
    rmsnorm_kernel<<<M_, 256, 0, stream>>>(x, ln2 + (size_t)l*D_, h);
    gemm256<1><<<dim3((F_/256)*(M_/256)), 512, 0, stream>>>(h, wt1, u, nullptr, M_, F_, D_);
    gemm_bt<1><<<(D_/128)*(M_/128), 256, 0, stream>>>(u, wt2, x, nullptr, x, M_, D_, F_);
  }

  rmsnorm_kernel<<<M_, 256, 0, stream>>>(x, nw, h);
  gemm256<0><<<dim3((V_/256)*(M_/256)), 512, 0, stream>>>(h, ebf, nullptr, out, M_, V_, D_);
}